// Round 12
// baseline (325.947 us; speedup 1.0000x reference)
//
#include <hip/hip_runtime.h>
#include <hip/hip_bf16.h>
#include <stdint.h>

#define DIM 768
#define NTOK 4096

typedef __bf16 bf16x8_t __attribute__((ext_vector_type(8)));
typedef float f32x4_t __attribute__((ext_vector_type(4)));
typedef unsigned short u16x8 __attribute__((ext_vector_type(8)));

__device__ __forceinline__ float bf2f(unsigned short u) {
    union { unsigned int i; float f; } v; v.i = ((unsigned int)u) << 16; return v.f;
}
__device__ __forceinline__ unsigned short f2bf(float f) {
    union { float f; unsigned int i; } v; v.f = f;
    unsigned int x = v.i;
    unsigned int r = x + 0x7fffu + ((x >> 16) & 1u);
    return (unsigned short)(r >> 16);
}
__device__ __forceinline__ u16x8 pack8(const float4& a, const float4& b) {
    u16x8 o;
    o[0] = f2bf(a.x); o[1] = f2bf(a.y); o[2] = f2bf(a.z); o[3] = f2bf(a.w);
    o[4] = f2bf(b.x); o[5] = f2bf(b.y); o[6] = f2bf(b.z); o[7] = f2bf(b.w);
    return o;
}

// ---------------- fused prep: 3x weight cvt + accumulator zero ----------------
__global__ __launch_bounds__(256) void prep(
    const float* __restrict__ qkw, const float* __restrict__ fc1w, const float* __restrict__ fc2w,
    unsigned short* __restrict__ oqk, unsigned short* __restrict__ ofc1,
    unsigned short* __restrict__ ofc2, float* __restrict__ zbuf)
{
    const int b = blockIdx.x, t = threadIdx.x;
    const float* src; unsigned short* dst; int rel;
    if (b < 1152)      { src = qkw;  dst = oqk;  rel = b; }
    else if (b < 3456) { src = fc1w; dst = ofc1; rel = b - 1152; }
    else if (b < 5760) { src = fc2w; dst = ofc2; rel = b - 3456; }
    else { zbuf[(b - 5760) * 256 + t] = 0.f; return; }
    int i = rel * 1024 + t * 4;
    float4 v = *(const float4*)&src[i];
    ushort4 o;
    o.x = f2bf(v.x); o.y = f2bf(v.y); o.z = f2bf(v.z); o.w = f2bf(v.w);
    *(ushort4*)&dst[i] = o;
}

// ---------------- depthwise conv 3x3 + residual + optional LN ----------------
template<int DO_LN, int BASE_BF16, int CIN_BF16, int PRE_BF16>
__global__ __launch_bounds__(256) void conv_ln(
    const void* __restrict__ base_, const void* __restrict__ cin_,
    const float* __restrict__ cw, const float* __restrict__ cb,
    const float* __restrict__ lnw, const float* __restrict__ lnb,
    void* __restrict__ pre_out, unsigned short* __restrict__ lnb16_out)
{
    const int n = blockIdx.x;
    const int hh = n >> 6, ww = n & 63;
    const int t = threadIdx.x;
    float s[3];
#pragma unroll
    for (int i = 0; i < 3; i++) {
        int c = t + i * 256;
        float acc = cb[c];
#pragma unroll
        for (int dh = -1; dh <= 1; dh++) {
            int h2 = hh + dh;
            if ((unsigned)h2 < 64u) {
#pragma unroll
                for (int dw = -1; dw <= 1; dw++) {
                    int w2 = ww + dw;
                    if ((unsigned)w2 < 64u) {
                        size_t idx = (size_t)(h2 * 64 + w2) * DIM + c;
                        float cv = CIN_BF16 ? bf2f(((const unsigned short*)cin_)[idx])
                                            : ((const float*)cin_)[idx];
                        acc = fmaf(cv, cw[c * 9 + (dh + 1) * 3 + (dw + 1)], acc);
                    }
                }
            }
        }
        size_t idx = (size_t)n * DIM + c;
        float v = (BASE_BF16 ? bf2f(((const unsigned short*)base_)[idx])
                             : ((const float*)base_)[idx]) + acc;
        s[i] = v;
        if (pre_out) {
            if (PRE_BF16) ((unsigned short*)pre_out)[idx] = f2bf(v);
            else          ((float*)pre_out)[idx] = v;
        }
    }
    if (DO_LN) {
        float s1 = s[0] + s[1] + s[2];
        float s2 = s[0] * s[0] + s[1] * s[1] + s[2] * s[2];
#pragma unroll
        for (int o = 32; o; o >>= 1) { s1 += __shfl_xor(s1, o); s2 += __shfl_xor(s2, o); }
        __shared__ float red[8];
        int w = t >> 6, lane = t & 63;
        if (lane == 0) { red[w * 2] = s1; red[w * 2 + 1] = s2; }
        __syncthreads();
        s1 = red[0] + red[2] + red[4] + red[6];
        s2 = red[1] + red[3] + red[5] + red[7];
        float mean = s1 * (1.f / 768.f);
        float var = s2 * (1.f / 768.f) - mean * mean;
        float rstd = rsqrtf(var + 1e-5f);
#pragma unroll
        for (int i = 0; i < 3; i++) {
            int c = t + i * 256;
            float vn = (s[i] - mean) * rstd * lnw[c] + lnb[c];
            lnb16_out[(size_t)n * DIM + c] = f2bf(vn);
        }
    }
}

// ---------------- bf16 MFMA GEMM: barrier-free, LDS-free, per-wave 64x64 tiles --------------
// C[M,N] = act(A[M,K] @ B[N,K]^T + bias) (+add). Block = 4 waves = 128x128 tile.
// Fragments loaded DIRECTLY from global (16 rows x 64B per load instr). K-step 32, depth-2.
// XCD 2D chunking: per-XCD chunk = PR brows x PC bcols, XC = NBX/PC.
template<int NBX, int PR, int PC, int SILU, int OUTBF16, int ADD, int ADDBF16, int ROPE>
__global__ __launch_bounds__(256, 2) void gemm_nb(
    const unsigned short* __restrict__ A, const unsigned short* __restrict__ B,
    const float* __restrict__ bias, const void* __restrict__ addsrc,
    void* __restrict__ outp,
    unsigned short* __restrict__ qr, unsigned short* __restrict__ krs,
    unsigned short* __restrict__ qpre, float* __restrict__ ksum,
    int N, int K)
{
    constexpr int XC = NBX / PC;
    const int xcd = blockIdx.x & 7, local = blockIdx.x >> 3;
    const int brow = (xcd / XC) * PR + local / PC;
    const int bcol = (xcd % XC) * PC + local % PC;
    const int t = threadIdx.x, w = t >> 6, lane = t & 63;
    const int wr = w >> 1, wc = w & 1;          // 2x2 wave grid
    const int fr = lane & 15;
    const int kc = (lane >> 4) * 8;             // k element offset within 32-slice

    const unsigned short* pa[4];
#pragma unroll
    for (int m = 0; m < 4; m++)
        pa[m] = A + (size_t)(brow * 128 + wr * 64 + m * 16 + fr) * K + kc;
    const unsigned short* pb[4];
#pragma unroll
    for (int n = 0; n < 4; n++)
        pb[n] = B + (size_t)(bcol * 128 + wc * 64 + n * 16 + fr) * K + kc;

    f32x4_t acc[4][4];
#pragma unroll
    for (int m = 0; m < 4; m++)
#pragma unroll
        for (int n = 0; n < 4; n++) acc[m][n] = (f32x4_t){0.f, 0.f, 0.f, 0.f};

    bf16x8_t fa[2][4], fb[2][4];    // two NAMED stages, literal indices only (rule #20)
#define LOADS(s, kof) do { \
    _Pragma("unroll") for (int m_ = 0; m_ < 4; m_++) fa[s][m_] = *(const bf16x8_t*)(pa[m_] + (kof)); \
    _Pragma("unroll") for (int n_ = 0; n_ < 4; n_++) fb[s][n_] = *(const bf16x8_t*)(pb[n_] + (kof)); } while (0)
#define MM(s) do { \
    __builtin_amdgcn_s_setprio(1); \
    _Pragma("unroll") for (int m_ = 0; m_ < 4; m_++) \
        _Pragma("unroll") for (int n_ = 0; n_ < 4; n_++) \
            acc[m_][n_] = __builtin_amdgcn_mfma_f32_16x16x32_bf16(fa[s][m_], fb[s][n_], acc[m_][n_], 0, 0, 0); \
    __builtin_amdgcn_s_setprio(0); } while (0)

    const int nt = K >> 5;          // 24 or 96 (even)
    LOADS(0, 0);
    LOADS(1, 32);
    for (int kk = 0; kk < nt; kk += 2) {
        MM(0);
        if (kk + 2 < nt) LOADS(0, (kk + 2) * 32);
        MM(1);
        if (kk + 3 < nt) LOADS(1, (kk + 3) * 32);
    }
#undef LOADS
#undef MM

    const int rb = brow * 128 + wr * 64 + (lane >> 4) * 4;
    const int cb = bcol * 128 + wc * 64 + fr;

    if constexpr (ROPE) {
        // fused ELU+1, axial RoPE, ksum. q blocks: bcol<6; k blocks: bcol>=6.
        const bool isq = (bcol < 6);
        const bool use_h = ((bcol % 6) < 3);       // feature (col mod 768) < 384 -> row-pos
#pragma unroll
        for (int n = 0; n < 4; n++) {
            int col = cb + n * 16;
            float bs = bias[col];
            int cm = isq ? col : col - 768;        // feature index 0..767
            int p = cm >> 1;                        // pair index 0..383
            int pmv = use_h ? p : p - 192;
            float th = __expf(-(float)pmv * (9.210340371976184f / 192.f));
            float kssum = 0.f;
#pragma unroll
            for (int m = 0; m < 4; m++) {
#pragma unroll
                for (int j = 0; j < 4; j++) {
                    int row = rb + m * 16 + j;
                    float v = acc[m][n][j] + bs;
                    float e = v > 0.f ? v + 1.f : __expf(v);
                    float pe = __shfl_xor(e, 1);
                    float pos = use_h ? (float)(row >> 6) : (float)(row & 63);
                    float sa, ca;
                    __sincosf(pos * th, &sa, &ca);
                    float rot = (fr & 1) ? (pe * sa + e * ca) : (e * ca - pe * sa);
                    if (isq) {
                        qr[(size_t)row * 768 + col] = f2bf(rot);
                        qpre[(size_t)row * 768 + col] = f2bf(e);
                    } else {
                        krs[(size_t)row * 768 + cm] = f2bf(rot * 0.015625f);
                        kssum += e;
                    }
                }
            }
            if (!isq) {
                kssum += __shfl_xor(kssum, 16);
                kssum += __shfl_xor(kssum, 32);
                if (lane < 16) atomicAdd(&ksum[cm], kssum);
            }
        }
    } else {
#pragma unroll
        for (int n = 0; n < 4; n++) {
            int col = cb + n * 16;
            float bs = bias ? bias[col] : 0.f;
#pragma unroll
            for (int m = 0; m < 4; m++) {
#pragma unroll
                for (int j = 0; j < 4; j++) {
                    int row = rb + m * 16 + j;
                    float v = acc[m][n][j] + bs;
                    if (SILU) v = v / (1.f + __expf(-v));
                    if (ADD) {
                        size_t idx = (size_t)row * N + col;
                        v += ADDBF16 ? bf2f(((const unsigned short*)addsrc)[idx])
                                     : ((const float*)addsrc)[idx];
                    }
                    if (OUTBF16) ((unsigned short*)outp)[(size_t)row * N + col] = f2bf(v);
                    else ((float*)outp)[(size_t)row * N + col] = v;
                }
            }
        }
    }
}

// ---------------- kvT[h][e][d] = sum_n (v*s)[n,e] (k_rope*s)[n,d], atomic partials ----------------
__global__ __launch_bounds__(256) void kv_accum(
    const unsigned short* __restrict__ krs, const unsigned short* __restrict__ x1b,
    float* __restrict__ kvout)
{
    const int chunk = blockIdx.x, h = blockIdx.y;
    const int n0 = chunk * 128;
    __shared__ float kl[128][64];
    __shared__ float vl[128][64];
    const int t = threadIdx.x;
    const int r = t >> 1, cs = (t & 1) * 32;
#pragma unroll
    for (int j = 0; j < 32; j += 8) {
        u16x8 kk = *(const u16x8*)&krs[(size_t)(n0 + r) * DIM + h * 64 + cs + j];
        u16x8 vv = *(const u16x8*)&x1b[(size_t)(n0 + r) * DIM + h * 64 + cs + j];
#pragma unroll
        for (int e = 0; e < 8; e++) {
            kl[r][cs + j + e] = bf2f(kk[e]);
            vl[r][cs + j + e] = bf2f(vv[e]) * 0.015625f;
        }
    }
    __syncthreads();
    const int td = t >> 4, te = t & 15;
    float a[4][4] = {};
    for (int nn = 0; nn < 128; nn++) {
        f32x4_t kd = *(const f32x4_t*)&kl[nn][td * 4];
        f32x4_t ve = *(const f32x4_t*)&vl[nn][te * 4];
#pragma unroll
        for (int i = 0; i < 4; i++)
#pragma unroll
            for (int j = 0; j < 4; j++)
                a[i][j] = fmaf(kd[i], ve[j], a[i][j]);
    }
#pragma unroll
    for (int i = 0; i < 4; i++)
#pragma unroll
        for (int j = 0; j < 4; j++)
            atomicAdd(&kvout[h * 4096 + (te * 4 + j) * 64 + (td * 4 + i)], a[i][j]);
}

// ---------------- a = (q_rope @ kv) * z (MFMA) fused with x2 = x + a + lepe(x1) ----------------
__global__ __launch_bounds__(256) void attn_lepe(
    const unsigned short* __restrict__ qr, const unsigned short* __restrict__ qpre,
    const float* __restrict__ ksum, const float* __restrict__ kvT,
    const float* __restrict__ x, const unsigned short* __restrict__ x1b,
    const float* __restrict__ lepe_w, const float* __restrict__ lepe_b,
    unsigned short* __restrict__ x2b)
{
    const int h = blockIdx.y;
    const int chunk = blockIdx.x;
    const int n0 = chunk * 128;
    const int c0 = h * 64;
    const int R0 = chunk * 2;
    const int t = threadIdx.x, w = t >> 6, lane = t & 63;
    __shared__ __align__(128) unsigned short kvL[64 * 64];
    __shared__ __align__(128) unsigned short x1L[4][64][64];
    __shared__ float zl[128];
    __shared__ float kmL[64];

    {
        const int e = t >> 2, db = (t & 3) * 16;
        const float* src = &kvT[h * 4096 + e * 64 + db];
        float4 v0 = *(const float4*)&src[0];
        float4 v1 = *(const float4*)&src[4];
        float4 v2 = *(const float4*)&src[8];
        float4 v3 = *(const float4*)&src[12];
        int s0 = ((db >> 3) + 0) ^ (e & 7);
        int s1 = ((db >> 3) + 1) ^ (e & 7);
        *(u16x8*)((char*)kvL + e * 128 + s0 * 16) = pack8(v0, v1);
        *(u16x8*)((char*)kvL + e * 128 + s1 * 16) = pack8(v2, v3);
    }
    {
        const int r = t >> 6, ww = t & 63;
        const int rr = R0 - 1 + r;
        const bool ok = (unsigned)rr < 64u;
        const unsigned short* sp = &x1b[(size_t)(rr * 64 + ww) * DIM + c0];
#pragma unroll
        for (int jj = 0; jj < 8; jj++) {
            u16x8 vv;
            if (ok) vv = *(const u16x8*)(sp + jj * 8);
            else    vv = (u16x8)(0);
            *(u16x8*)&x1L[r][ww][jj * 8] = vv;
        }
    }
    if (t < 64) kmL[t] = ksum[h * 64 + t] * (1.f / 4096.f);
    __syncthreads();

    {
        const int tok = t >> 1, half = (t & 1) * 32;
        const unsigned short* qp = &qpre[(size_t)(n0 + tok) * DIM + c0 + half];
        float zs = 0.f;
#pragma unroll
        for (int j = 0; j < 32; j += 8) {
            u16x8 qv = *(const u16x8*)&qp[j];
#pragma unroll
            for (int e = 0; e < 8; e++) zs = fmaf(bf2f(qv[e]), kmL[half + j + e], zs);
        }
        zs += __shfl_xor(zs, 1);
        if ((t & 1) == 0) zl[tok] = 1.f / (zs + 1e-6f);
    }
    __syncthreads();

    const int fr = lane & 15;
    const int kc = (lane >> 4) * 8;
    const unsigned short* qbase = qr + (size_t)(n0 + w * 32 + fr) * DIM + c0 + kc;

    f32x4_t acc[2][4];
#pragma unroll
    for (int m = 0; m < 2; m++)
#pragma unroll
        for (int n = 0; n < 4; n++) acc[m][n] = (f32x4_t){0.f, 0.f, 0.f, 0.f};

#pragma unroll
    for (int ks = 0; ks < 2; ks++) {
        bf16x8_t af[2], bfv[4];
#pragma unroll
        for (int m = 0; m < 2; m++)
            af[m] = *(const bf16x8_t*)(qbase + (size_t)m * 16 * DIM + ks * 32);
#pragma unroll
        for (int n = 0; n < 4; n++) {
            int e = n * 16 + fr;
            int slot = (ks * 4 + (lane >> 4)) ^ (e & 7);
            bfv[n] = *(const bf16x8_t*)((const char*)kvL + e * 128 + slot * 16);
        }
#pragma unroll
        for (int m = 0; m < 2; m++)
#pragma unroll
            for (int n = 0; n < 4; n++)
                acc[m][n] = __builtin_amdgcn_mfma_f32_16x16x32_bf16(af[m], bfv[n], acc[m][n], 0, 0, 0);
    }

    const int r4 = (lane >> 4) * 4;
#pragma unroll
    for (int n = 0; n < 4; n++) {
        const int cc = n * 16 + fr;
        const int c = c0 + cc;
        float w9[9];
#pragma unroll
        for (int q2 = 0; q2 < 9; q2++) w9[q2] = lepe_w[c * 9 + q2];
        const float lb = lepe_b[c];
#pragma unroll
        for (int m = 0; m < 2; m++) {
#pragma unroll
            for (int j = 0; j < 4; j++) {
                const int tr = w * 32 + m * 16 + r4 + j;
                float av = acc[m][n][j] * zl[tr];
                const int ww = tr & 63;
                const int rbase = (tr >> 6) + 1;
                float conv = 0.f;
#pragma unroll
                for (int dh = -1; dh <= 1; dh++) {
#pragma unroll
                    for (int dw = -1; dw <= 1; dw++) {
                        int w2 = ww + dw;
                        if ((unsigned)w2 < 64u)
                            conv = fmaf(bf2f(x1L[rbase + dh][w2][cc]),
                                        w9[(dh + 1) * 3 + (dw + 1)], conv);
                    }
                }
                float xr2 = x[(size_t)(n0 + tr) * DIM + c];
                x2b[(size_t)(n0 + tr) * DIM + c] = f2bf(xr2 + av + conv + lb);
            }
        }
    }
}

extern "C" void kernel_launch(void* const* d_in, const int* in_sizes, int n_in,
                              void* d_out, int out_size, void* d_ws, size_t ws_size,
                              hipStream_t stream) {
    (void)in_sizes; (void)n_in; (void)out_size; (void)ws_size;
    const float* x       = (const float*)d_in[0];
    const float* cpe1_w  = (const float*)d_in[1];
    const float* cpe1_b  = (const float*)d_in[2];
    const float* norm1_w = (const float*)d_in[3];
    const float* norm1_b = (const float*)d_in[4];
    const float* qk_w    = (const float*)d_in[5];
    const float* qk_b    = (const float*)d_in[6];
    const float* lepe_w  = (const float*)d_in[7];
    const float* lepe_b  = (const float*)d_in[8];
    const float* cpe2_w  = (const float*)d_in[9];
    const float* cpe2_b  = (const float*)d_in[10];
    const float* norm2_w = (const float*)d_in[11];
    const float* norm2_b = (const float*)d_in[12];
    const float* fc1_w   = (const float*)d_in[13];
    const float* fc1_b   = (const float*)d_in[14];
    const float* fc2_w   = (const float*)d_in[15];
    const float* fc2_b   = (const float*)d_in[16];
    char* ws = (char*)d_ws;

    constexpr size_t o_qkwb  = 0;
    constexpr size_t o_fc1wb = o_qkwb  + (size_t)1536 * 768 * 2;
    constexpr size_t o_fc2wb = o_fc1wb + (size_t)3072 * 768 * 2;
    constexpr size_t o_x1b   = o_fc2wb + (size_t)768 * 3072 * 2;
    constexpr size_t o_big   = o_x1b   + (size_t)4096 * 768 * 2;   // 25 MB region, reused
    constexpr size_t o_qr    = o_big   + (size_t)4096 * 3072 * 2;
    constexpr size_t o_krs   = o_qr    + (size_t)4096 * 768 * 2;
    constexpr size_t o_qpre  = o_krs   + (size_t)4096 * 768 * 2;
    constexpr size_t o_ksum  = o_qpre  + (size_t)4096 * 768 * 2;
    constexpr size_t o_kv    = o_ksum  + (size_t)768 * 4;
    constexpr size_t o_x3b   = o_kv    + (size_t)12 * 64 * 64 * 4;
    constexpr size_t o_yb    = o_x3b   + (size_t)4096 * 768 * 2;

    unsigned short* x2b = (unsigned short*)(ws + o_big);   // 6.3 MB, written by attn, read by conv5
    unsigned short* h_b = (unsigned short*)(ws + o_big);   // 25 MB fc1 out (after conv5 consumed x2b)

    // 0. prep: weight cvt + zero accumulators (ksum + kv)
    prep<<<5955, 256, 0, stream>>>(qk_w, fc1_w, fc2_w,
                                   (unsigned short*)(ws + o_qkwb), (unsigned short*)(ws + o_fc1wb),
                                   (unsigned short*)(ws + o_fc2wb), (float*)(ws + o_ksum));
    // 1. x1 = LN(x + cpe1(x)) -> bf16
    conv_ln<1, 0, 0, 0><<<4096, 256, 0, stream>>>(x, x, cpe1_w, cpe1_b, norm1_w, norm1_b,
                                                  nullptr, (unsigned short*)(ws + o_x1b));
    // 2. qk GEMM + fused elu/rope/ksum -> qr, krs, qpre   (384 blocks, barrier-free)
    gemm_nb<12, 8, 6, 0, 0, 0, 0, 1><<<384, 256, 0, stream>>>(
        (const unsigned short*)(ws + o_x1b), (const unsigned short*)(ws + o_qkwb),
        qk_b, nullptr, nullptr,
        (unsigned short*)(ws + o_qr), (unsigned short*)(ws + o_krs),
        (unsigned short*)(ws + o_qpre), (float*)(ws + o_ksum),
        1536, 768);
    // 3. kv accumulation (writes kvT[h][e][d])
    kv_accum<<<dim3(32, 12), 256, 0, stream>>>((const unsigned short*)(ws + o_krs),
                                               (const unsigned short*)(ws + o_x1b),
                                               (float*)(ws + o_kv));
    // 4. attn MFMA + fused lepe/x residual -> x2 bf16
    attn_lepe<<<dim3(32, 12), 256, 0, stream>>>((const unsigned short*)(ws + o_qr),
                                                (const unsigned short*)(ws + o_qpre),
                                                (const float*)(ws + o_ksum), (const float*)(ws + o_kv),
                                                x, (const unsigned short*)(ws + o_x1b),
                                                lepe_w, lepe_b, x2b);
    // 5. x3 = x2 + cpe2(x2) -> bf16 ; y = LN(x3) -> bf16
    conv_ln<1, 1, 1, 1><<<4096, 256, 0, stream>>>(x2b, x2b, cpe2_w, cpe2_b, norm2_w, norm2_b,
                                                  (void*)(ws + o_x3b), (unsigned short*)(ws + o_yb));
    // 6. h = silu(y @ fc1^T + b1)   (768 blocks)
    gemm_nb<24, 8, 12, 1, 1, 0, 0, 0><<<768, 256, 0, stream>>>(
        (const unsigned short*)(ws + o_yb), (const unsigned short*)(ws + o_fc1wb),
        fc1_b, nullptr, h_b, nullptr, nullptr, nullptr, nullptr,
        3072, 768);
    // 7. out = x3 + h @ fc2^T + b2   (192 blocks, K=3072)
    gemm_nb<6, 4, 6, 0, 0, 1, 1, 0><<<192, 256, 0, stream>>>(
        h_b, (const unsigned short*)(ws + o_fc2wb),
        fc2_b, (const void*)(ws + o_x3b), d_out, nullptr, nullptr, nullptr, nullptr,
        768, 3072);
}

// Round 13
// 178.489 us; speedup vs baseline: 1.8261x; 1.8261x over previous
//
#include <hip/hip_runtime.h>
#include <hip/hip_bf16.h>
#include <stdint.h>

#define DIM 768
#define NTOK 4096

typedef __bf16 bf16x8_t __attribute__((ext_vector_type(8)));
typedef float f32x4_t __attribute__((ext_vector_type(4)));
typedef unsigned short u16x8 __attribute__((ext_vector_type(8)));

__device__ __forceinline__ float bf2f(unsigned short u) {
    union { unsigned int i; float f; } v; v.i = ((unsigned int)u) << 16; return v.f;
}
__device__ __forceinline__ unsigned short f2bf(float f) {
    union { float f; unsigned int i; } v; v.f = f;
    unsigned int x = v.i;
    unsigned int r = x + 0x7fffu + ((x >> 16) & 1u);
    return (unsigned short)(r >> 16);
}
__device__ __forceinline__ u16x8 pack8(const float4& a, const float4& b) {
    u16x8 o;
    o[0] = f2bf(a.x); o[1] = f2bf(a.y); o[2] = f2bf(a.z); o[3] = f2bf(a.w);
    o[4] = f2bf(b.x); o[5] = f2bf(b.y); o[6] = f2bf(b.z); o[7] = f2bf(b.w);
    return o;
}

__device__ __forceinline__ void wait_lgkm0() {
    asm volatile("s_waitcnt lgkmcnt(0)" ::: "memory");
    __builtin_amdgcn_sched_barrier(0);
}

// ---------------- fused prep: 3x weight cvt + accumulator zero ----------------
__global__ __launch_bounds__(256) void prep(
    const float* __restrict__ qkw, const float* __restrict__ fc1w, const float* __restrict__ fc2w,
    unsigned short* __restrict__ oqk, unsigned short* __restrict__ ofc1,
    unsigned short* __restrict__ ofc2, float* __restrict__ zbuf)
{
    const int b = blockIdx.x, t = threadIdx.x;
    const float* src; unsigned short* dst; int rel;
    if (b < 1152)      { src = qkw;  dst = oqk;  rel = b; }
    else if (b < 3456) { src = fc1w; dst = ofc1; rel = b - 1152; }
    else if (b < 5760) { src = fc2w; dst = ofc2; rel = b - 3456; }
    else { zbuf[(b - 5760) * 256 + t] = 0.f; return; }
    int i = rel * 1024 + t * 4;
    float4 v = *(const float4*)&src[i];
    ushort4 o;
    o.x = f2bf(v.x); o.y = f2bf(v.y); o.z = f2bf(v.z); o.w = f2bf(v.w);
    *(ushort4*)&dst[i] = o;
}

// ---------------- depthwise conv 3x3 + residual + optional LN (vectorized x4) ----------------
// 192 threads/block, thread t owns channels [4t, 4t+4).
template<int DO_LN, int BASE_BF16, int CIN_BF16, int PRE_BF16>
__global__ __launch_bounds__(192) void conv_ln(
    const void* __restrict__ base_, const void* __restrict__ cin_,
    const float* __restrict__ cw, const float* __restrict__ cb,
    const float* __restrict__ lnw, const float* __restrict__ lnb,
    void* __restrict__ pre_out, unsigned short* __restrict__ lnb16_out)
{
    const int n = blockIdx.x;
    const int hh = n >> 6, ww = n & 63;
    const int t = threadIdx.x;
    const int c = t * 4;

    // hoist per-channel tap weights (L2-hot, 27 KB tensor)
    float w9[4][9];
#pragma unroll
    for (int j = 0; j < 4; j++)
#pragma unroll
        for (int q = 0; q < 9; q++) w9[j][q] = cw[(c + j) * 9 + q];

    float acc[4];
#pragma unroll
    for (int j = 0; j < 4; j++) acc[j] = cb[c + j];

#pragma unroll
    for (int dh = -1; dh <= 1; dh++) {
        int h2 = hh + dh;
        if ((unsigned)h2 < 64u) {
#pragma unroll
            for (int dw = -1; dw <= 1; dw++) {
                int w2 = ww + dw;
                if ((unsigned)w2 < 64u) {
                    size_t idx = (size_t)(h2 * 64 + w2) * DIM + c;
                    float cv[4];
                    if (CIN_BF16) {
                        ushort4 u = *(const ushort4*)((const unsigned short*)cin_ + idx);
                        cv[0] = bf2f(u.x); cv[1] = bf2f(u.y); cv[2] = bf2f(u.z); cv[3] = bf2f(u.w);
                    } else {
                        float4 u = *(const float4*)((const float*)cin_ + idx);
                        cv[0] = u.x; cv[1] = u.y; cv[2] = u.z; cv[3] = u.w;
                    }
                    const int q = (dh + 1) * 3 + (dw + 1);
#pragma unroll
                    for (int j = 0; j < 4; j++) acc[j] = fmaf(cv[j], w9[j][q], acc[j]);
                }
            }
        }
    }

    size_t bidx = (size_t)n * DIM + c;
    float s[4];
    {
        float bv[4];
        if (BASE_BF16) {
            ushort4 u = *(const ushort4*)((const unsigned short*)base_ + bidx);
            bv[0] = bf2f(u.x); bv[1] = bf2f(u.y); bv[2] = bf2f(u.z); bv[3] = bf2f(u.w);
        } else {
            float4 u = *(const float4*)((const float*)base_ + bidx);
            bv[0] = u.x; bv[1] = u.y; bv[2] = u.z; bv[3] = u.w;
        }
#pragma unroll
        for (int j = 0; j < 4; j++) s[j] = bv[j] + acc[j];
    }
    if (pre_out) {
        if (PRE_BF16) {
            ushort4 o;
            o.x = f2bf(s[0]); o.y = f2bf(s[1]); o.z = f2bf(s[2]); o.w = f2bf(s[3]);
            *(ushort4*)((unsigned short*)pre_out + bidx) = o;
        } else {
            *(float4*)((float*)pre_out + bidx) = make_float4(s[0], s[1], s[2], s[3]);
        }
    }
    if (DO_LN) {
        float s1 = s[0] + s[1] + s[2] + s[3];
        float s2 = s[0] * s[0] + s[1] * s[1] + s[2] * s[2] + s[3] * s[3];
#pragma unroll
        for (int o = 32; o; o >>= 1) { s1 += __shfl_xor(s1, o); s2 += __shfl_xor(s2, o); }
        __shared__ float red[6];
        int w = t >> 6, lane = t & 63;
        if (lane == 0) { red[w * 2] = s1; red[w * 2 + 1] = s2; }
        __syncthreads();
        s1 = red[0] + red[2] + red[4];
        s2 = red[1] + red[3] + red[5];
        float mean = s1 * (1.f / 768.f);
        float var = s2 * (1.f / 768.f) - mean * mean;
        float rstd = rsqrtf(var + 1e-5f);
        ushort4 o;
        float vn0 = (s[0] - mean) * rstd * lnw[c + 0] + lnb[c + 0];
        float vn1 = (s[1] - mean) * rstd * lnw[c + 1] + lnb[c + 1];
        float vn2 = (s[2] - mean) * rstd * lnw[c + 2] + lnb[c + 2];
        float vn3 = (s[3] - mean) * rstd * lnw[c + 3] + lnb[c + 3];
        o.x = f2bf(vn0); o.y = f2bf(vn1); o.z = f2bf(vn2); o.w = f2bf(vn3);
        *(ushort4*)(lnb16_out + bidx) = o;
    }
}

// ---------------- bf16 MFMA GEMM: depth-2 register pipeline (STATIC sets), 1 barrier/K-step ----
// C[M,N] = act(A[M,K] @ B[N,K]^T + bias) (+add). BK=64, 8 waves. nt must be even, >= 4.
// XCD 2D chunking: per-XCD chunk = PR brows x PC bcols, XC = NBX/PC.
template<int BM, int BN, int NBX, int PR, int PC, int SILU, int OUTBF16, int ADD, int ADDBF16, int ROPE>
__global__ __launch_bounds__(512, 2) void gemm_bt(
    const unsigned short* __restrict__ A, const unsigned short* __restrict__ B,
    const float* __restrict__ bias, const void* __restrict__ addsrc,
    void* __restrict__ outp,
    unsigned short* __restrict__ qr, unsigned short* __restrict__ krs,
    unsigned short* __restrict__ qpre, float* __restrict__ ksum,
    int N, int K)
{
    constexpr int WC  = BN / 64;
    constexpr int WR  = 8 / WC;
    constexpr int RB  = BM / WR;
    constexpr int MF  = RB / 16;
    constexpr int ACW = BM / 64;
    constexpr int BCW = BN / 64;
    constexpr int XC  = NBX / PC;
    __shared__ __align__(128) unsigned short aL[2][BM * 64];
    __shared__ __align__(128) unsigned short bL[2][BN * 64];

    const int xcd = blockIdx.x & 7, local = blockIdx.x >> 3;
    const int brow = (xcd / XC) * PR + local / PC;
    const int bcol = (xcd % XC) * PC + local % PC;
    const int t = threadIdx.x, w = t >> 6, lane = t & 63;
    const int wr = w / WC, wc = w % WC;
    const int lr = lane >> 3;
    const int sl = lane & 7;
    const int swz = ((sl ^ lr) << 4) + lr * 128;

    const unsigned short* aSrc[ACW];
#pragma unroll
    for (int i = 0; i < ACW; i++)
        aSrc[i] = A + (size_t)(brow * BM + (w * ACW + i) * 8 + lr) * K + sl * 8;
    const unsigned short* bSrc[BCW];
#pragma unroll
    for (int i = 0; i < BCW; i++)
        bSrc[i] = B + (size_t)(bcol * BN + (w * BCW + i) * 8 + lr) * K + sl * 8;

    f32x4_t acc[MF][4];
#pragma unroll
    for (int m = 0; m < MF; m++)
#pragma unroll
        for (int n = 0; n < 4; n++) acc[m][n] = (f32x4_t){0.f, 0.f, 0.f, 0.f};

    // two NAMED register sets -> every index compile-time (rule #20)
    u16x8 rA0[ACW], rB0[BCW], rA1[ACW], rB1[BCW];
#define LOADT0(k0) do { \
    _Pragma("unroll") for (int i_ = 0; i_ < ACW; i_++) rA0[i_] = *(const u16x8*)(aSrc[i_] + (k0)); \
    _Pragma("unroll") for (int i_ = 0; i_ < BCW; i_++) rB0[i_] = *(const u16x8*)(bSrc[i_] + (k0)); } while (0)
#define LOADT1(k0) do { \
    _Pragma("unroll") for (int i_ = 0; i_ < ACW; i_++) rA1[i_] = *(const u16x8*)(aSrc[i_] + (k0)); \
    _Pragma("unroll") for (int i_ = 0; i_ < BCW; i_++) rB1[i_] = *(const u16x8*)(bSrc[i_] + (k0)); } while (0)
#define WRITET0(buf) do { \
    _Pragma("unroll") for (int i_ = 0; i_ < ACW; i_++) \
        *(u16x8*)((char*)aL[buf] + (w * ACW + i_) * 1024 + swz) = rA0[i_]; \
    _Pragma("unroll") for (int i_ = 0; i_ < BCW; i_++) \
        *(u16x8*)((char*)bL[buf] + (w * BCW + i_) * 1024 + swz) = rB0[i_]; } while (0)
#define WRITET1(buf) do { \
    _Pragma("unroll") for (int i_ = 0; i_ < ACW; i_++) \
        *(u16x8*)((char*)aL[buf] + (w * ACW + i_) * 1024 + swz) = rA1[i_]; \
    _Pragma("unroll") for (int i_ = 0; i_ < BCW; i_++) \
        *(u16x8*)((char*)bL[buf] + (w * BCW + i_) * 1024 + swz) = rB1[i_]; } while (0)

    const int fr = lane & 15;
    const int xr = (fr & 7) << 4;
    const int cbase = (lane >> 4) << 4;
#define COMPUTE(buf) do { \
    const char* ab_ = (const char*)aL[buf]; \
    const char* bb_ = (const char*)bL[buf]; \
    _Pragma("unroll") for (int ks = 0; ks < 2; ks++) { \
        bf16x8_t af[MF], bfv[4]; \
        _Pragma("unroll") for (int m = 0; m < MF; m++) \
            af[m] = *(const bf16x8_t*)(ab_ + (((wr * RB + m * 16 + fr) * 128 + cbase + ks * 64) ^ xr)); \
        _Pragma("unroll") for (int n = 0; n < 4; n++) \
            bfv[n] = *(const bf16x8_t*)(bb_ + (((wc * 64 + n * 16 + fr) * 128 + cbase + ks * 64) ^ xr)); \
        __builtin_amdgcn_s_setprio(1); \
        _Pragma("unroll") for (int m = 0; m < MF; m++) \
            _Pragma("unroll") for (int n = 0; n < 4; n++) \
                acc[m][n] = __builtin_amdgcn_mfma_f32_16x16x32_bf16(af[m], bfv[n], acc[m][n], 0, 0, 0); \
        __builtin_amdgcn_s_setprio(0); \
    } } while (0)

    const int nt = K >> 6;                 // 12 or 48: even, >= 4
    LOADT0(0);
    LOADT1(64);
    WRITET0(0);
    LOADT0(128);
    wait_lgkm0();
    __builtin_amdgcn_s_barrier();

    for (int tt = 0; tt < nt; tt += 2) {
        WRITET1(1);
        if (tt + 3 < nt) LOADT1((tt + 3) * 64);
        COMPUTE(0);
        wait_lgkm0();
        __builtin_amdgcn_s_barrier();
        if (tt + 2 < nt) WRITET0(0);
        if (tt + 4 < nt) LOADT0((tt + 4) * 64);
        COMPUTE(1);
        wait_lgkm0();
        __builtin_amdgcn_s_barrier();
    }
#undef LOADT0
#undef LOADT1
#undef WRITET0
#undef WRITET1
#undef COMPUTE

    const int rb = brow * BM + wr * RB + (lane >> 4) * 4;
    const int cb = bcol * BN + wc * 64 + fr;

    if constexpr (ROPE) {
        const bool isq = (bcol < 6);
        const bool use_h = ((bcol % 6) < 3);
#pragma unroll
        for (int n = 0; n < 4; n++) {
            int col = cb + n * 16;
            float bs = bias[col];
            int cm = isq ? col : col - 768;
            int p = cm >> 1;
            int pmv = use_h ? p : p - 192;
            float th = __expf(-(float)pmv * (9.210340371976184f / 192.f));
            float kssum = 0.f;
#pragma unroll
            for (int m = 0; m < MF; m++) {
#pragma unroll
                for (int j = 0; j < 4; j++) {
                    int row = rb + m * 16 + j;
                    float v = acc[m][n][j] + bs;
                    float e = v > 0.f ? v + 1.f : __expf(v);
                    float pe = __shfl_xor(e, 1);
                    float pos = use_h ? (float)(row >> 6) : (float)(row & 63);
                    float sa, ca;
                    __sincosf(pos * th, &sa, &ca);
                    float rot = (fr & 1) ? (pe * sa + e * ca) : (e * ca - pe * sa);
                    if (isq) {
                        qr[(size_t)row * 768 + col] = f2bf(rot);
                        qpre[(size_t)row * 768 + col] = f2bf(e);
                    } else {
                        krs[(size_t)row * 768 + cm] = f2bf(rot * 0.015625f);
                        kssum += e;
                    }
                }
            }
            if (!isq) {
                kssum += __shfl_xor(kssum, 16);
                kssum += __shfl_xor(kssum, 32);
                if (lane < 16) atomicAdd(&ksum[cm], kssum);
            }
        }
    } else {
#pragma unroll
        for (int n = 0; n < 4; n++) {
            int col = cb + n * 16;
            float bs = bias ? bias[col] : 0.f;
#pragma unroll
            for (int m = 0; m < MF; m++) {
#pragma unroll
                for (int j = 0; j < 4; j++) {
                    int row = rb + m * 16 + j;
                    float v = acc[m][n][j] + bs;
                    if (SILU) v = v / (1.f + __expf(-v));
                    if (ADD) {
                        size_t idx = (size_t)row * N + col;
                        v += ADDBF16 ? bf2f(((const unsigned short*)addsrc)[idx])
                                     : ((const float*)addsrc)[idx];
                    }
                    if (OUTBF16) ((unsigned short*)outp)[(size_t)row * N + col] = f2bf(v);
                    else ((float*)outp)[(size_t)row * N + col] = v;
                }
            }
        }
    }
}

// ---------------- kvT[h][e][d] = sum_n (v*s)[n,e] (k_rope*s)[n,d], atomic partials ----------------
__global__ __launch_bounds__(256) void kv_accum(
    const unsigned short* __restrict__ krs, const unsigned short* __restrict__ x1b,
    float* __restrict__ kvout)
{
    const int chunk = blockIdx.x, h = blockIdx.y;
    const int n0 = chunk * 128;
    __shared__ float kl[128][64];
    __shared__ float vl[128][64];
    const int t = threadIdx.x;
    const int r = t >> 1, cs = (t & 1) * 32;
#pragma unroll
    for (int j = 0; j < 32; j += 8) {
        u16x8 kk = *(const u16x8*)&krs[(size_t)(n0 + r) * DIM + h * 64 + cs + j];
        u16x8 vv = *(const u16x8*)&x1b[(size_t)(n0 + r) * DIM + h * 64 + cs + j];
#pragma unroll
        for (int e = 0; e < 8; e++) {
            kl[r][cs + j + e] = bf2f(kk[e]);
            vl[r][cs + j + e] = bf2f(vv[e]) * 0.015625f;
        }
    }
    __syncthreads();
    const int td = t >> 4, te = t & 15;
    float a[4][4] = {};
    for (int nn = 0; nn < 128; nn++) {
        f32x4_t kd = *(const f32x4_t*)&kl[nn][td * 4];
        f32x4_t ve = *(const f32x4_t*)&vl[nn][te * 4];
#pragma unroll
        for (int i = 0; i < 4; i++)
#pragma unroll
            for (int j = 0; j < 4; j++)
                a[i][j] = fmaf(kd[i], ve[j], a[i][j]);
    }
#pragma unroll
    for (int i = 0; i < 4; i++)
#pragma unroll
        for (int j = 0; j < 4; j++)
            atomicAdd(&kvout[h * 4096 + (te * 4 + j) * 64 + (td * 4 + i)], a[i][j]);
}

// ---------------- a = (q_rope @ kv) * z (MFMA) fused with x2 = x + a + lepe(x1) ----------------
__global__ __launch_bounds__(256) void attn_lepe(
    const unsigned short* __restrict__ qr, const unsigned short* __restrict__ qpre,
    const float* __restrict__ ksum, const float* __restrict__ kvT,
    const float* __restrict__ x, const unsigned short* __restrict__ x1b,
    const float* __restrict__ lepe_w, const float* __restrict__ lepe_b,
    unsigned short* __restrict__ x2b)
{
    const int h = blockIdx.y;
    const int chunk = blockIdx.x;
    const int n0 = chunk * 128;
    const int c0 = h * 64;
    const int R0 = chunk * 2;
    const int t = threadIdx.x, w = t >> 6, lane = t & 63;
    __shared__ __align__(128) unsigned short kvL[64 * 64];
    __shared__ __align__(128) unsigned short x1L[4][64][64];
    __shared__ float zl[128];
    __shared__ float kmL[64];

    {
        const int e = t >> 2, db = (t & 3) * 16;
        const float* src = &kvT[h * 4096 + e * 64 + db];
        float4 v0 = *(const float4*)&src[0];
        float4 v1 = *(const float4*)&src[4];
        float4 v2 = *(const float4*)&src[8];
        float4 v3 = *(const float4*)&src[12];
        int s0 = ((db >> 3) + 0) ^ (e & 7);
        int s1 = ((db >> 3) + 1) ^ (e & 7);
        *(u16x8*)((char*)kvL + e * 128 + s0 * 16) = pack8(v0, v1);
        *(u16x8*)((char*)kvL + e * 128 + s1 * 16) = pack8(v2, v3);
    }
    {
        const int r = t >> 6, ww = t & 63;
        const int rr = R0 - 1 + r;
        const bool ok = (unsigned)rr < 64u;
        const unsigned short* sp = &x1b[(size_t)(rr * 64 + ww) * DIM + c0];
#pragma unroll
        for (int jj = 0; jj < 8; jj++) {
            u16x8 vv;
            if (ok) vv = *(const u16x8*)(sp + jj * 8);
            else    vv = (u16x8)(0);
            *(u16x8*)&x1L[r][ww][jj * 8] = vv;
        }
    }
    if (t < 64) kmL[t] = ksum[h * 64 + t] * (1.f / 4096.f);
    __syncthreads();

    {
        const int tok = t >> 1, half = (t & 1) * 32;
        const unsigned short* qp = &qpre[(size_t)(n0 + tok) * DIM + c0 + half];
        float zs = 0.f;
#pragma unroll
        for (int j = 0; j < 32; j += 8) {
            u16x8 qv = *(const u16x8*)&qp[j];
#pragma unroll
            for (int e = 0; e < 8; e++) zs = fmaf(bf2f(qv[e]), kmL[half + j + e], zs);
        }
        zs += __shfl_xor(zs, 1);
        if ((t & 1) == 0) zl[tok] = 1.f / (zs + 1e-6f);
    }
    __syncthreads();

    const int fr = lane & 15;
    const int kc = (lane >> 4) * 8;
    const unsigned short* qbase = qr + (size_t)(n0 + w * 32 + fr) * DIM + c0 + kc;

    f32x4_t acc[2][4];
#pragma unroll
    for (int m = 0; m < 2; m++)
#pragma unroll
        for (int n = 0; n < 4; n++) acc[m][n] = (f32x4_t){0.f, 0.f, 0.f, 0.f};

#pragma unroll
    for (int ks = 0; ks < 2; ks++) {
        bf16x8_t af[2], bfv[4];
#pragma unroll
        for (int m = 0; m < 2; m++)
            af[m] = *(const bf16x8_t*)(qbase + (size_t)m * 16 * DIM + ks * 32);
#pragma unroll
        for (int n = 0; n < 4; n++) {
            int e = n * 16 + fr;
            int slot = (ks * 4 + (lane >> 4)) ^ (e & 7);
            bfv[n] = *(const bf16x8_t*)((const char*)kvL + e * 128 + slot * 16);
        }
#pragma unroll
        for (int m = 0; m < 2; m++)
#pragma unroll
            for (int n = 0; n < 4; n++)
                acc[m][n] = __builtin_amdgcn_mfma_f32_16x16x32_bf16(af[m], bfv[n], acc[m][n], 0, 0, 0);
    }

    const int r4 = (lane >> 4) * 4;
#pragma unroll
    for (int n = 0; n < 4; n++) {
        const int cc = n * 16 + fr;
        const int c = c0 + cc;
        float w9[9];
#pragma unroll
        for (int q2 = 0; q2 < 9; q2++) w9[q2] = lepe_w[c * 9 + q2];
        const float lb = lepe_b[c];
#pragma unroll
        for (int m = 0; m < 2; m++) {
#pragma unroll
            for (int j = 0; j < 4; j++) {
                const int tr = w * 32 + m * 16 + r4 + j;
                float av = acc[m][n][j] * zl[tr];
                const int ww = tr & 63;
                const int rbase = (tr >> 6) + 1;
                float conv = 0.f;
#pragma unroll
                for (int dh = -1; dh <= 1; dh++) {
#pragma unroll
                    for (int dw = -1; dw <= 1; dw++) {
                        int w2 = ww + dw;
                        if ((unsigned)w2 < 64u)
                            conv = fmaf(bf2f(x1L[rbase + dh][w2][cc]),
                                        w9[(dh + 1) * 3 + (dw + 1)], conv);
                    }
                }
                float xr2 = x[(size_t)(n0 + tr) * DIM + c];
                x2b[(size_t)(n0 + tr) * DIM + c] = f2bf(xr2 + av + conv + lb);
            }
        }
    }
}

extern "C" void kernel_launch(void* const* d_in, const int* in_sizes, int n_in,
                              void* d_out, int out_size, void* d_ws, size_t ws_size,
                              hipStream_t stream) {
    (void)in_sizes; (void)n_in; (void)out_size; (void)ws_size;
    const float* x       = (const float*)d_in[0];
    const float* cpe1_w  = (const float*)d_in[1];
    const float* cpe1_b  = (const float*)d_in[2];
    const float* norm1_w = (const float*)d_in[3];
    const float* norm1_b = (const float*)d_in[4];
    const float* qk_w    = (const float*)d_in[5];
    const float* qk_b    = (const float*)d_in[6];
    const float* lepe_w  = (const float*)d_in[7];
    const float* lepe_b  = (const float*)d_in[8];
    const float* cpe2_w  = (const float*)d_in[9];
    const float* cpe2_b  = (const float*)d_in[10];
    const float* norm2_w = (const float*)d_in[11];
    const float* norm2_b = (const float*)d_in[12];
    const float* fc1_w   = (const float*)d_in[13];
    const float* fc1_b   = (const float*)d_in[14];
    const float* fc2_w   = (const float*)d_in[15];
    const float* fc2_b   = (const float*)d_in[16];
    char* ws = (char*)d_ws;

    constexpr size_t o_qkwb  = 0;
    constexpr size_t o_fc1wb = o_qkwb  + (size_t)1536 * 768 * 2;
    constexpr size_t o_fc2wb = o_fc1wb + (size_t)3072 * 768 * 2;
    constexpr size_t o_x1b   = o_fc2wb + (size_t)768 * 3072 * 2;
    constexpr size_t o_big   = o_x1b   + (size_t)4096 * 768 * 2;   // 25 MB region, reused
    constexpr size_t o_qr    = o_big   + (size_t)4096 * 3072 * 2;
    constexpr size_t o_krs   = o_qr    + (size_t)4096 * 768 * 2;
    constexpr size_t o_qpre  = o_krs   + (size_t)4096 * 768 * 2;
    constexpr size_t o_ksum  = o_qpre  + (size_t)4096 * 768 * 2;
    constexpr size_t o_kv    = o_ksum  + (size_t)768 * 4;
    constexpr size_t o_x3b   = o_kv    + (size_t)12 * 64 * 64 * 4;
    constexpr size_t o_yb    = o_x3b   + (size_t)4096 * 768 * 2;

    unsigned short* x2b = (unsigned short*)(ws + o_big);   // 6.3 MB, written by attn, read by conv5
    unsigned short* h_b = (unsigned short*)(ws + o_big);   // 25 MB fc1 out (after conv5 consumed x2b)

    // 0. prep: weight cvt + zero accumulators (ksum + kv)
    prep<<<5955, 256, 0, stream>>>(qk_w, fc1_w, fc2_w,
                                   (unsigned short*)(ws + o_qkwb), (unsigned short*)(ws + o_fc1wb),
                                   (unsigned short*)(ws + o_fc2wb), (float*)(ws + o_ksum));
    // 1. x1 = LN(x + cpe1(x)) -> bf16
    conv_ln<1, 0, 0, 0><<<4096, 192, 0, stream>>>(x, x, cpe1_w, cpe1_b, norm1_w, norm1_b,
                                                  nullptr, (unsigned short*)(ws + o_x1b));
    // 2. qk GEMM + fused elu/rope/ksum -> qr, krs, qpre
    gemm_bt<256, 128, 12, 2, 12, 0, 0, 0, 0, 1><<<192, 512, 0, stream>>>(
        (const unsigned short*)(ws + o_x1b), (const unsigned short*)(ws + o_qkwb),
        qk_b, nullptr, nullptr,
        (unsigned short*)(ws + o_qr), (unsigned short*)(ws + o_krs),
        (unsigned short*)(ws + o_qpre), (float*)(ws + o_ksum),
        1536, 768);
    // 3. kv accumulation (writes kvT[h][e][d])
    kv_accum<<<dim3(32, 12), 256, 0, stream>>>((const unsigned short*)(ws + o_krs),
                                               (const unsigned short*)(ws + o_x1b),
                                               (float*)(ws + o_kv));
    // 4. attn MFMA + fused lepe/x residual -> x2 bf16
    attn_lepe<<<dim3(32, 12), 256, 0, stream>>>((const unsigned short*)(ws + o_qr),
                                                (const unsigned short*)(ws + o_qpre),
                                                (const float*)(ws + o_ksum), (const float*)(ws + o_kv),
                                                x, (const unsigned short*)(ws + o_x1b),
                                                lepe_w, lepe_b, x2b);
    // 5. x3 = x2 + cpe2(x2) -> bf16 ; y = LN(x3) -> bf16
    conv_ln<1, 1, 1, 1><<<4096, 192, 0, stream>>>(x2b, x2b, cpe2_w, cpe2_b, norm2_w, norm2_b,
                                                  (void*)(ws + o_x3b), (unsigned short*)(ws + o_yb));
    // 6. h = silu(y @ fc1^T + b1)
    gemm_bt<256, 128, 24, 4, 12, 1, 1, 0, 0, 0><<<384, 512, 0, stream>>>(
        (const unsigned short*)(ws + o_yb), (const unsigned short*)(ws + o_fc1wb),
        fc1_b, nullptr, h_b, nullptr, nullptr, nullptr, nullptr,
        3072, 768);
    // 7. out = x3 + h @ fc2^T + b2
    gemm_bt<128, 128, 6, 4, 6, 0, 0, 1, 1, 0><<<192, 512, 0, stream>>>(
        h_b, (const unsigned short*)(ws + o_fc2wb),
        fc2_b, (const void*)(ws + o_x3b), d_out, nullptr, nullptr, nullptr, nullptr,
        768, 3072);
}